// Round 8
// baseline (382.206 us; speedup 1.0000x reference)
//
#include <hip/hip_runtime.h>

// Problem constants (fixed by reference): B=2, N=8192, C=80
constexpr int NB = 2;
constexpr int NN = 8192;
constexpr int NC = 80;
constexpr int ROWS = NN + 1;  // mask rows per batch; row NN is an all-zero row

// d_out layout (floats), in reference return order:
// boxes[B,N,4], max_scores[B,N], labels[B,N], keep[B,N], all_scores[B,N,C]
constexpr size_t OFF_BOXES  = 0;
constexpr size_t OFF_SCORES = (size_t)NB * NN * 4;
constexpr size_t OFF_LABELS = OFF_SCORES + (size_t)NB * NN;
constexpr size_t OFF_KEEP   = OFF_LABELS + (size_t)NB * NN;
constexpr size_t OFF_ALL    = OFF_KEEP + (size_t)NB * NN;

// d_ws layout
constexpr size_t WS_KEYS  = 0;                                   // B*N u64
constexpr size_t WS_VBYTE = WS_KEYS + (size_t)NB * NN * 8;       // B*N u8
constexpr size_t WS_ORDER = WS_VBYTE + (size_t)NB * NN;          // B*N i32
constexpr size_t WS_SBOX  = WS_ORDER + (size_t)NB * NN * 4;      // B*N float4
constexpr size_t WS_VBITS = WS_SBOX + (size_t)NB * NN * 16;      // B*128 u64
constexpr size_t WS_MASK  = WS_VBITS + (size_t)NB * 128 * 8;     // B*ROWS*128 u64
constexpr size_t WS_DNM   = WS_MASK + (size_t)NB * ROWS * 128 * 8; // B*128*4*64 u64
constexpr size_t WS_PART  = WS_DNM + (size_t)NB * 128 * 4 * 64 * 8; // B*8*N i32
constexpr size_t WS_TOTAL = WS_PART + (size_t)NB * 8 * NN * 4;
constexpr size_t WS_TOTAL_OLD = WS_PART;
// Sparse-NMS extension (keepw reuses the dead keys region):
constexpr unsigned CSR_CAP = 1u << 20;  // entries per batch (u16 each)
constexpr size_t WS_RD  = WS_TOTAL;                               // B*N u64
constexpr size_t WS_CSR = WS_RD + (size_t)NB * NN * 8;            // B*(CAP+16) u16
constexpr size_t WS_CNT = WS_CSR + (size_t)NB * (CSR_CAP + 16) * 2;  // counters
constexpr size_t WS_TOTAL_SPARSE = WS_CNT + 64;
constexpr int DNM_WORDS = NB * 128 * 4 * 64;  // 65536
constexpr int NSEG = 8;                       // rank column segments

typedef unsigned long long u64;
typedef __attribute__((ext_vector_type(2))) unsigned long long u64x2;

// lgkmcnt(0)-only barrier: keeps global loads in flight across it.
__device__ inline void lbar() {
  __builtin_amdgcn_s_waitcnt(0xc07f);
  __builtin_amdgcn_s_barrier();
}

__device__ inline u64 readlane64(u64 v, int src) {
  unsigned int lo = (unsigned int)__builtin_amdgcn_readlane((int)(unsigned int)v, src);
  unsigned int hi = (unsigned int)__builtin_amdgcn_readlane((int)(unsigned int)(v >> 32), src);
  return ((u64)hi << 32) | lo;
}

__device__ inline u64 readfirstlane64(u64 v) {
  unsigned int lo = (unsigned int)__builtin_amdgcn_readfirstlane((int)(unsigned int)v);
  unsigned int hi = (unsigned int)__builtin_amdgcn_readfirstlane((int)(unsigned int)(v >> 32));
  return ((u64)hi << 32) | lo;
}

// IoU exactly mirroring the numpy op order; contraction off so f32 rounding
// matches numpy bit-for-bit. Bit-exactly SYMMETRIC in (p,q).
__device__ inline float iou_pair(const float4 p, const float4 q) {
#pragma clang fp contract(off)
  float areaA = (p.z - p.x) * (p.w - p.y);
  float areaB = (q.z - q.x) * (q.w - q.y);
  float ix1 = fmaxf(p.x, q.x);
  float iy1 = fmaxf(p.y, q.y);
  float ix2 = fminf(p.z, q.z);
  float iy2 = fminf(p.w, q.w);
  float inter = fmaxf(ix2 - ix1, 0.0f) * fmaxf(iy2 - iy1, 0.0f);
  float uni = areaA + areaB - inter;
  return inter / fmaxf(uni, 1e-9f);
}

__device__ inline float clip01(float v) { return fminf(fmaxf(v, 0.0f), 1.0f); }

// One wave per (b,n): sigmoid all 80 classes, max/argmax (first-index ties),
// box decode, validity, sort key. Also zero-inits vbits.
__global__ __launch_bounds__(256) void decode_kernel(
    const float* __restrict__ logits, const float4* __restrict__ deltas,
    const float4* __restrict__ anchors, float4* __restrict__ boxes_out,
    float* __restrict__ scores_out, float* __restrict__ labels_out,
    float* __restrict__ all_out, u64* __restrict__ keys,
    unsigned char* __restrict__ vbyte, u64* __restrict__ vbits) {
#pragma clang fp contract(off)
  if (blockIdx.x == 0 && threadIdx.x < NB * 128) vbits[threadIdx.x] = 0ull;
  int wid = (blockIdx.x * 256 + threadIdx.x) >> 6;  // 0 .. B*N-1
  int lane = threadIdx.x & 63;
  int n = wid & (NN - 1);
  size_t base = (size_t)wid * NC;

  float x0 = logits[base + lane];
  float sig0 = 1.0f / (1.0f + expf(-x0));
  all_out[base + lane] = sig0;
  float bs = sig0;
  int bidx = lane;
  if (lane < NC - 64) {
    float x1 = logits[base + 64 + lane];
    float sig1 = 1.0f / (1.0f + expf(-x1));
    all_out[base + 64 + lane] = sig1;
    if (sig1 > bs) { bs = sig1; bidx = lane + 64; }  // tie -> smaller idx wins
  }
  for (int off = 32; off; off >>= 1) {
    float os = __shfl_xor(bs, off, 64);
    int oi = __shfl_xor(bidx, off, 64);
    if (os > bs || (os == bs && oi < bidx)) { bs = os; bidx = oi; }
  }
  if (lane == 0) {
    float4 d = deltas[wid];
    float4 a = anchors[n];
    float aw = a.z - a.x, ah = a.w - a.y;
    float acx = a.x + 0.5f * aw, acy = a.y + 0.5f * ah;
    float dw = fminf(d.z, 4.0f), dh = fminf(d.w, 4.0f);
    float pcx = d.x * aw + acx;
    float pcy = d.y * ah + acy;
    float pw = expf(dw) * aw;
    float ph = expf(dh) * ah;
    float4 bx;
    bx.x = clip01(pcx - 0.5f * pw);
    bx.y = clip01(pcy - 0.5f * ph);
    bx.z = clip01(pcx + 0.5f * pw);
    bx.w = clip01(pcy + 0.5f * ph);
    boxes_out[wid] = bx;
    scores_out[wid] = bs;
    labels_out[wid] = (float)bidx;
    float bw = bx.z - bx.x, bh = bx.w - bx.y;
    bool valid = (bs > 0.5f) && (bw > 0.01f) && (bh > 0.01f) &&
                 (bw < 0.99f) && (bh < 0.99f);
    vbyte[wid] = valid ? 1 : 0;
    keys[wid] = ((u64)__float_as_uint(bs) << 32) | (unsigned int)(NN - 1 - n);
  }
}

// Rank pass 1: partial counts over a column SEGMENT. Also zero-inits dnm
// and (if provided) the CSR counters.
__global__ __launch_bounds__(1024) void rank_part_kernel(
    const u64* __restrict__ keys, int* __restrict__ part,
    u64* __restrict__ dnm, unsigned int* cnt, unsigned int* ovf) {
  int b = blockIdx.z, seg = blockIdx.y, rb = blockIdx.x;
  int gid = ((blockIdx.z * NSEG + blockIdx.y) * gridDim.x + blockIdx.x) * 1024 +
            threadIdx.x;
  if (gid < DNM_WORDS) dnm[gid] = 0ull;
  if (cnt && gid < NB) { cnt[gid] = 0u; ovf[gid] = 0u; }
  int r = threadIdx.x & 255;   // row slot
  int q = threadIdx.x >> 8;    // column quarter 0..3 (wave-uniform)
  int i = rb * 256 + r;
  const u64* kb = keys + (size_t)b * NN;
  u64 myk = kb[i];
  int cnt2 = 0;
  int j0 = seg * (NN / NSEG) + q * (NN / NSEG / 4);
  int j1 = j0 + NN / NSEG / 4;  // 256 iterations
#pragma unroll 8
  for (int j = j0; j < j1; ++j) {
    u64 kj = kb[j];  // wave-uniform address -> scalar load
    cnt2 += (kj > myk) ? 1 : 0;
  }
  __shared__ unsigned short partl[4][256];
  partl[q][r] = (unsigned short)cnt2;
  __syncthreads();
  if (threadIdx.x < 256) {
    int s = partl[0][r] + partl[1][r] + partl[2][r] + partl[3][r];
    part[((size_t)b * NSEG + seg) * NN + i] = s;
  }
}

// Rank pass 2: rank = sum of segment partials; scatter order/sbox/vbits.
__global__ __launch_bounds__(256) void rank_final_kernel(
    const int* __restrict__ part, const float4* __restrict__ boxes,
    const unsigned char* __restrict__ vbyte, int* __restrict__ order,
    float4* __restrict__ sbox, u64* __restrict__ vbits) {
  int b = blockIdx.y;
  int i = blockIdx.x * 256 + threadIdx.x;
  const int* pb = part + (size_t)b * NSEG * NN + i;
  int rank = 0;
#pragma unroll
  for (int s = 0; s < NSEG; ++s) rank += pb[(size_t)s * NN];
  order[(size_t)b * NN + rank] = i;
  sbox[(size_t)b * NN + rank] = boxes[(size_t)b * NN + i];
  if (vbyte[(size_t)b * NN + i])
    atomicOr(&vbits[b * 128 + (rank >> 6)], 1ull << (rank & 63));
}

// Monolithic rank (fallback path only, when ws can't hold part[]).
__global__ __launch_bounds__(1024) void rank_kernel(
    const u64* __restrict__ keys, const float4* __restrict__ boxes,
    const unsigned char* __restrict__ vbyte, int* __restrict__ order,
    float4* __restrict__ sbox, u64* __restrict__ vbits,
    u64* __restrict__ dnm) {
  int b = blockIdx.y;
  int gid = (blockIdx.y * gridDim.x + blockIdx.x) * 1024 + threadIdx.x;
  for (int z = gid; z < DNM_WORDS; z += 65536) dnm[z] = 0ull;
  int r = threadIdx.x & 255;
  int q = threadIdx.x >> 8;
  int i = blockIdx.x * 256 + r;
  const u64* kb = keys + (size_t)b * NN;
  u64 myk = kb[i];
  int cnt = 0;
  int j0 = q * (NN / 4), j1 = j0 + NN / 4;
#pragma unroll 8
  for (int j = j0; j < j1; ++j) {
    u64 kj = kb[j];
    cnt += (kj > myk) ? 1 : 0;
  }
  __shared__ unsigned short part[4][256];
  part[q][r] = (unsigned short)cnt;
  __syncthreads();
  if (threadIdx.x < 256) {
    int rank = part[0][r] + part[1][r] + part[2][r] + part[3][r];
    order[(size_t)b * NN + rank] = i;
    sbox[(size_t)b * NN + rank] = boxes[(size_t)b * NN + i];
    if (vbyte[(size_t)b * NN + i])
      atomicOr(&vbits[b * 128 + (rank >> 6)], 1ull << (rank & 63));
  }
}

// 64x64 tile of the (sorted-order) suppression matrix. Triangular grid.
// Diagonal tiles: upper half (self cleared) to mask[], lower half to dnm
// slot 0 (fixpoint masks). Off-diag bx>by: full word to mask[]; dq<4 also
// to dnm. Mask row i holds valid words only for bx >= i>>6.
__global__ __launch_bounds__(64) void build_kernel(
    const float4* __restrict__ sbox, u64* __restrict__ mask,
    u64* __restrict__ dnm) {
  int byq = blockIdx.y, bxq = blockIdx.x, b = blockIdx.z;
  int by, bx;
  if (bxq >= byq) {
    by = byq; bx = bxq;
  } else if (byq == 64) {
    return;
  } else {
    by = 128 - byq; bx = 127 - bxq;
  }
  int lane = threadIdx.x;
  __shared__ float4 cb[64];
  cb[lane] = sbox[(size_t)b * NN + bx * 64 + lane];
  __syncthreads();
  int i = by * 64 + lane;
  float4 rb = sbox[(size_t)b * NN + i];
  u64 word = 0;
  if (bx == by) {
    for (int jj = 0; jj < 64; ++jj)
      if (iou_pair(rb, cb[jj]) > 0.5f) word |= 1ull << jj;
    word &= ~(1ull << lane);  // clear self-IoU bit
    u64 lmask = (1ull << lane) - 1ull;
    mask[((size_t)b * ROWS + i) * 128 + bx] = word & ~lmask;
    dnm[(((size_t)b * 128 + by) * 4 + 0) * 64 + lane] = word & lmask;
  } else {
    for (int jj = 0; jj < 64; ++jj)
      if (iou_pair(rb, cb[jj]) > 0.5f) word |= 1ull << jj;
    mask[((size_t)b * ROWS + i) * 128 + bx] = word;
    int dq = bx - by;
    if (dq < 4) dnm[(((size_t)b * 128 + by) * 4 + dq) * 64 + lane] = word;
  }
}

// CSR fill: one WAVE per sorted row. Reads the row's valid mask words
// (>= diag chunk), wave-scans popcounts, reserves 16B-aligned space via one
// atomicAdd, writes u16 column indices. rd[row] = off | (deg<<32).
// The suppression matrix is ~3 mean upper-degree -> total ~25-70K entries
// per batch vs CSR_CAP=1M; overflow sets ovf[b] (dense fallback runs).
__global__ __launch_bounds__(1024) void fill_csr(
    const u64* __restrict__ mask, u64* __restrict__ rd,
    unsigned short* __restrict__ csr, unsigned int* __restrict__ cnt,
    unsigned int* __restrict__ ovf) {
  int lane = threadIdx.x & 63;
  int gw = blockIdx.x * 16 + (threadIdx.x >> 6);  // 0 .. NB*NN-1
  int b = gw >> 13;
  int r = gw & (NN - 1);
  const u64* row = mask + ((size_t)b * ROWS + r) * 128;
  int cd = r >> 6;
  int w0 = 2 * lane;
  u64x2 v = *(const u64x2*)(row + w0);  // contiguous 1KB per wave
  u64 x0 = (w0 >= cd) ? v[0] : 0ull;
  u64 x1 = (w0 + 1 >= cd) ? v[1] : 0ull;
  int c2 = __popcll(x0) + __popcll(x1);
  int pre = c2;
  for (int off = 1; off < 64; off <<= 1) {
    int t = __shfl_up(pre, off, 64);
    if (lane >= off) pre += t;
  }
  int excl = pre - c2;
  int tot = __shfl(pre, 63, 64);
  unsigned atot = ((unsigned)tot + 7u) & ~7u;  // 16B-aligned reservation
  unsigned base = 0;
  if (lane == 0 && tot > 0) base = atomicAdd(&cnt[b], atot);
  base = (unsigned)__shfl((int)base, 0, 64);
  bool ok = (base + atot <= CSR_CAP);
  if (lane == 0) {
    if (tot > 0 && !ok) atomicOr(&ovf[b], 1u);
    rd[(size_t)b * NN + r] = ok ? ((u64)base | ((u64)(unsigned)tot << 32)) : 0ull;
  }
  if (ok && tot > 0) {
    unsigned short* dst = csr + (size_t)b * (CSR_CAP + 16) + base + excl;
    int k = 0;
    u64 t0 = x0;
    while (t0) {
      int bit = __builtin_ctzll(t0);
      dst[k++] = (unsigned short)(w0 * 64 + bit);
      t0 &= t0 - 1;
    }
    u64 t1 = x1;
    while (t1) {
      int bit = __builtin_ctzll(t1);
      dst[k++] = (unsigned short)((w0 + 1) * 64 + bit);
      t1 &= t1 - 1;
    }
  }
}

// Sparse greedy reduce: ONE 64-lane wave per batch. Per chunk c:
//  - ballot fixpoint on the lower-triangle diag mask (dnm slot 0)
//  - each KEPT lane deposits its own row's CSR entries (all j>r with
//    IoU>0.5) straight into s_remv via LDS atomicOr.
// No background waves, no barriers, no mask-row streaming. A 4-load/body
// asm pipeline (rd[c+4], 16 entries[c+2] x2, diag[c+2]) with counted
// vmcnt(4) keeps everything 2 bodies ahead; deg>16 takes a rare slow path
// (its compiler drain only makes counted waits trivially satisfied).
__global__ __launch_bounds__(64) void reduce_sparse(
    const u64* __restrict__ vbits, const u64* __restrict__ dnm,
    const u64* __restrict__ rdarr, const unsigned short* __restrict__ csr,
    const unsigned int* __restrict__ ovf, u64* __restrict__ keepw) {
  int b = blockIdx.x, lane = threadIdx.x;
  if (ovf[b]) return;  // dense fallback handles this batch
  __shared__ u64 s_remv[128];
  __shared__ u64 s_keep[128];
  s_remv[2 * lane] = 0ull;
  s_remv[2 * lane + 1] = 0ull;
  u64 va = vbits[b * 128 + 2 * lane];
  u64 vb2 = vbits[b * 128 + 2 * lane + 1];
  const u64* dnb = dnm + (size_t)b * 128 * 4 * 64;
  const u64* rdb = rdarr + (size_t)b * NN;
  const unsigned short* cb = csr + (size_t)b * (CSR_CAP + 16);

  // Prologue (plain loads, then full drain):
  u64 rdv0 = rdb[lane];
  u64 rdv1 = rdb[64 + lane];
  u64 rdS2 = rdb[128 + lane];
  u64 rdS3 = rdb[192 + lane];
  unsigned offS0 = (unsigned)rdv0; int degS0 = (int)(rdv0 >> 32);
  unsigned offS1 = (unsigned)rdv1; int degS1 = (int)(rdv1 >> 32);
  u64 dS0 = dnb[lane];
  u64 dS1 = dnb[4 * 64 + lane];
  u64x2 eaS0 = *(const u64x2*)(cb + offS0);
  u64x2 ebS0 = *(const u64x2*)(cb + offS0 + 8);
  u64x2 eaS1 = *(const u64x2*)(cb + offS1);
  u64x2 ebS1 = *(const u64x2*)(cb + offS1 + 8);
  u64 rdS0 = 0, rdS1 = 0, dS2 = 0, dS3 = 0;
  u64x2 eaS2{}, ebS2{}, eaS3{}, ebS3{};
  unsigned offS2 = 0, offS3 = 0;
  int degS2 = 0, degS3 = 0;
  __syncthreads();
  asm volatile("s_waitcnt vmcnt(0)" ::: "memory");
  __builtin_amdgcn_sched_barrier(0);

  auto body = [&](int c, u64x2 ea, u64x2 eb, u64 dcur, unsigned offCur,
                  int degCur, u64 rdNext, u64& rdOut, u64x2& eaOut,
                  u64x2& ebOut, u64& dOut, unsigned& offOut, int& degOut) {
    // everything issued at body <= c-2 is complete (4 loads/body)
    asm volatile("s_waitcnt vmcnt(4)"
                 : "+v"(ea), "+v"(eb), "+v"(dcur), "+v"(rdNext)
                 :
                 : "memory");
    __builtin_amdgcn_sched_barrier(0);
    offOut = (unsigned)rdNext;        // chunk c+2's per-lane CSR offset
    degOut = (int)(rdNext >> 32);
    int cp2 = (c + 2 < 128) ? c + 2 : 127;
    int cp4 = (c + 4 < 128) ? c + 4 : 127;
    u64 a_rd = (u64)(uintptr_t)(rdb + (size_t)cp4 * 64 + lane);
    u64 a_e = (u64)(uintptr_t)(cb + offOut);
    u64 a_d = (u64)(uintptr_t)(dnb + ((size_t)cp2 * 4) * 64 + lane);
    asm volatile(
        "global_load_dwordx2 %0, %4, off\n\t"
        "global_load_dwordx4 %1, %5, off\n\t"
        "global_load_dwordx4 %2, %5, off offset:16\n\t"
        "global_load_dwordx2 %3, %6, off"
        : "=&v"(rdOut), "=&v"(eaOut), "=&v"(ebOut), "=&v"(dOut)
        : "v"(a_rd), "v"(a_e), "v"(a_d)
        : "memory");
    u64 rm = s_remv[c];
    u64 vbw = readlane64((c & 1) ? vb2 : va, c >> 1);
    u64 cand = readfirstlane64(vbw & ~rm);
    u64 kept = cand;
    while (true) {
      u64 sup = __ballot((dcur & kept) != 0ull);
      u64 nk = cand & ~sup;
      if (nk == kept) break;
      kept = nk;
    }
    bool isk = (kept >> lane) & 1;
    if (isk && degCur > 0) {
      int kmax = degCur < 16 ? degCur : 16;
      u64 w0 = ea[0], w1 = ea[1], w2 = eb[0], w3 = eb[1];
#pragma unroll
      for (int k = 0; k < 16; ++k) {
        if (k < kmax) {
          u64 src = (k < 4) ? w0 : (k < 8) ? w1 : (k < 12) ? w2 : w3;
          int j = (int)((src >> (16 * (k & 3))) & 0xFFFFull);
          atomicOr(&s_remv[j >> 6], 1ull << (j & 63));
        }
      }
      for (int k = 16; k < degCur; ++k) {  // rare long-list slow path
        int j = cb[offCur + k];
        atomicOr(&s_remv[j >> 6], 1ull << (j & 63));
      }
    }
    if (lane == 0) s_keep[c] = kept;
  };

  for (int c = 0; c < 128; c += 4) {
    body(c + 0, eaS0, ebS0, dS0, offS0, degS0, rdS2, rdS0, eaS2, ebS2, dS2,
         offS2, degS2);
    body(c + 1, eaS1, ebS1, dS1, offS1, degS1, rdS3, rdS1, eaS3, ebS3, dS3,
         offS3, degS3);
    body(c + 2, eaS2, ebS2, dS2, offS2, degS2, rdS0, rdS2, eaS0, ebS0, dS0,
         offS0, degS0);
    body(c + 3, eaS3, ebS3, dS3, offS3, degS3, rdS1, rdS3, eaS1, ebS1, dS1,
         offS1, degS1);
  }

  asm volatile("s_waitcnt vmcnt(0)" ::: "memory");
  __syncthreads();
  keepw[b * 128 + 2 * lane] = s_keep[2 * lane];
  keepw[b * 128 + 2 * lane + 1] = s_keep[2 * lane + 1];
}

struct TSet {
  u64x2 t0, t1, t2, t3, t4, t5, t6, t7, t8, t9;
};

// Dense greedy reduce (v13 machinery) — now the overflow/small-ws fallback.
// If ovf != nullptr it runs ONLY when ovf[b] is set (CSR overflow).
__global__ __launch_bounds__(512) void reduce_dense(
    u64* __restrict__ mask, const u64* __restrict__ vbits,
    const u64* __restrict__ dnm, const unsigned int* __restrict__ ovf,
    u64* __restrict__ keepw) {
  int b = blockIdx.x, tid = threadIdx.x;
  if (ovf && ovf[b] == 0) return;
  int lane = tid & 63, wave = tid >> 6;
  __shared__ u64 s_remv[128];
  __shared__ u64 s_keep[128];
  __shared__ int s_rowlist[2][80];
  u64* mbz = mask + (size_t)b * ROWS * 128;
  const u64* mb = mbz;
  const u64* dn = dnm + (size_t)b * 128 * 4 * 64;

  for (int w = tid; w < 128; w += 512) {
    s_remv[w] = 0ull;
    mbz[(size_t)NN * 128 + w] = 0ull;  // zero row (dead-load target)
  }
  if (tid < 160) s_rowlist[tid / 80][tid % 80] = NN;

  u64 va = 0, vb2 = 0;
  u64 dA = 0, nA = 0, mA = 0, oA = 0, dB = 0, nB = 0, mB = 0, oB = 0;
  u64 dC = 0, nC = 0, mC = 0, oC = 0, dD = 0, nD = 0, mD = 0, oD = 0;
  if (wave == 0) {
    va = vbits[b * 128 + 2 * lane];
    vb2 = vbits[b * 128 + 2 * lane + 1];
    const u64* r0 = dn + lane;
    dA = r0[0]; nA = r0[64]; mA = r0[128]; oA = r0[192];
    const u64* r1 = dn + 4 * 64 + lane;
    dB = r1[0]; nB = r1[64]; mB = r1[128]; oB = r1[192];
  }
  TSet U{}, V{};
  int w0i = 2 * lane;
  __syncthreads();

  auto serial_body = [&](int c, u64 dcur, u64 ncur, u64 mcur, u64 ocur,
                         u64& dnew, u64& nnew, u64& mnew, u64& onew) {
    int cp = (c + 2 < 128) ? (c + 2) : 127;
    u64 pa = (u64)(uintptr_t)(dn + (size_t)cp * 4 * 64 + lane);
    asm volatile(
        "global_load_dwordx2 %0, %4, off\n\t"
        "global_load_dwordx2 %1, %4, off offset:512\n\t"
        "global_load_dwordx2 %2, %4, off offset:1024\n\t"
        "global_load_dwordx2 %3, %4, off offset:1536"
        : "=&v"(dnew), "=&v"(nnew), "=&v"(mnew), "=&v"(onew)
        : "v"(pa)
        : "memory");
    int par = c & 1;
    u64 rm = s_remv[c];
    u64 vbw = readlane64(par ? vb2 : va, c >> 1);
    u64 cand = readfirstlane64(vbw & ~rm);
    asm volatile("s_waitcnt vmcnt(8)"
                 : "+v"(dcur), "+v"(ncur), "+v"(mcur), "+v"(ocur)
                 :
                 : "memory");
    __builtin_amdgcn_sched_barrier(0);
    u64 kept = cand;
    while (true) {
      u64 sup = __ballot((dcur & kept) != 0ull);
      u64 nk = cand & ~sup;
      if (nk == kept) break;
      kept = nk;
    }
    bool isk = (kept >> lane) & 1;
    if (c + 1 < 128 && isk && ncur) atomicOr(&s_remv[c + 1], ncur);
    if (c + 2 < 128 && isk && mcur) atomicOr(&s_remv[c + 2], mcur);
    if (c + 3 < 128 && isk && ocur) atomicOr(&s_remv[c + 3], ocur);
    s_rowlist[par][lane] = NN;
    if (isk) {
      int pos = __popcll(kept & ((1ull << lane) - 1ull));
      s_rowlist[par][pos] = c * 64 + lane;
    }
    if (lane == 0) s_keep[c] = kept;
  };

  auto bg_body = [&](int c, TSet& T) {
    asm volatile("s_waitcnt vmcnt(10)"
                 : "+v"(T.t0), "+v"(T.t1), "+v"(T.t2), "+v"(T.t3), "+v"(T.t4),
                   "+v"(T.t5), "+v"(T.t6), "+v"(T.t7), "+v"(T.t8), "+v"(T.t9)
                 :
                 : "memory");
    __builtin_amdgcn_sched_barrier(0);
    u64 ax = T.t0[0] | T.t1[0] | T.t2[0] | T.t3[0] | T.t4[0] | T.t5[0] |
             T.t6[0] | T.t7[0] | T.t8[0] | T.t9[0];
    u64 ay = T.t0[1] | T.t1[1] | T.t2[1] | T.t3[1] | T.t4[1] | T.t5[1] |
             T.t6[1] | T.t7[1] | T.t8[1] | T.t9[1];
    int sc = (c + 1) & ~1;
    int wx = sc + w0i, wy = wx + 1;
    if (wx > c && wx < 128 && ax) atomicOr(&s_remv[wx], ax);
    if (wy > c && wy < 128 && ay) atomicOr(&s_remv[wy], ay);
    const int* rl = s_rowlist[(c - 1) & 1];
    int base = wave - 1;
    int si = (c + 3) & ~1;
    int w = si + w0i;
    bool wok = w < 128;
    const u64* mw = mb + w;
    u64 zaddr = (u64)(uintptr_t)(mbz + (size_t)NN * 128);
    int r0 = rl[base], r1 = rl[base + 7], r2 = rl[base + 14],
        r3 = rl[base + 21], r4 = rl[base + 28], r5 = rl[base + 35],
        r6 = rl[base + 42], r7 = rl[base + 49], r8 = rl[base + 56],
        r9 = rl[base + 63];
    u64 a0 = (wok && r0 != NN) ? (u64)(uintptr_t)(mw + (size_t)r0 * 128) : zaddr;
    u64 a1 = (wok && r1 != NN) ? (u64)(uintptr_t)(mw + (size_t)r1 * 128) : zaddr;
    u64 a2 = (wok && r2 != NN) ? (u64)(uintptr_t)(mw + (size_t)r2 * 128) : zaddr;
    u64 a3 = (wok && r3 != NN) ? (u64)(uintptr_t)(mw + (size_t)r3 * 128) : zaddr;
    u64 a4 = (wok && r4 != NN) ? (u64)(uintptr_t)(mw + (size_t)r4 * 128) : zaddr;
    u64 a5 = (wok && r5 != NN) ? (u64)(uintptr_t)(mw + (size_t)r5 * 128) : zaddr;
    u64 a6 = (wok && r6 != NN) ? (u64)(uintptr_t)(mw + (size_t)r6 * 128) : zaddr;
    u64 a7 = (wok && r7 != NN) ? (u64)(uintptr_t)(mw + (size_t)r7 * 128) : zaddr;
    u64 a8 = (wok && r8 != NN) ? (u64)(uintptr_t)(mw + (size_t)r8 * 128) : zaddr;
    u64 a9 = (wok && r9 != NN) ? (u64)(uintptr_t)(mw + (size_t)r9 * 128) : zaddr;
    asm volatile(
        "global_load_dwordx4 %0, %10, off\n\t"
        "global_load_dwordx4 %1, %11, off\n\t"
        "global_load_dwordx4 %2, %12, off\n\t"
        "global_load_dwordx4 %3, %13, off\n\t"
        "global_load_dwordx4 %4, %14, off\n\t"
        "global_load_dwordx4 %5, %15, off\n\t"
        "global_load_dwordx4 %6, %16, off\n\t"
        "global_load_dwordx4 %7, %17, off\n\t"
        "global_load_dwordx4 %8, %18, off\n\t"
        "global_load_dwordx4 %9, %19, off"
        : "=&v"(T.t0), "=&v"(T.t1), "=&v"(T.t2), "=&v"(T.t3), "=&v"(T.t4),
          "=&v"(T.t5), "=&v"(T.t6), "=&v"(T.t7), "=&v"(T.t8), "=&v"(T.t9)
        : "v"(a0), "v"(a1), "v"(a2), "v"(a3), "v"(a4), "v"(a5), "v"(a6),
          "v"(a7), "v"(a8), "v"(a9)
        : "memory");
  };

  for (int c = 0; c < 128; c += 4) {
    if (wave == 0) serial_body(c, dA, nA, mA, oA, dC, nC, mC, oC);
    else bg_body(c, U);
    lbar();
    if (wave == 0) serial_body(c + 1, dB, nB, mB, oB, dD, nD, mD, oD);
    else bg_body(c + 1, V);
    lbar();
    if (wave == 0) serial_body(c + 2, dC, nC, mC, oC, dA, nA, mA, oA);
    else bg_body(c + 2, U);
    lbar();
    if (wave == 0) serial_body(c + 3, dD, nD, mD, oD, dB, nB, mB, oB);
    else bg_body(c + 3, V);
    lbar();
  }

  asm volatile("s_waitcnt vmcnt(0)" ::: "memory");
  __syncthreads();
  for (int w = tid; w < 128; w += 512) keepw[b * 128 + w] = s_keep[w];
}

// Scatter keep bits back to original anchor order (parallel epilogue).
__global__ __launch_bounds__(256) void scatter_keep(
    const u64* __restrict__ keepw, const int* __restrict__ order,
    float* __restrict__ keep_out) {
  int b = blockIdx.y;
  int p = blockIdx.x * 256 + threadIdx.x;
  int orig = order[(size_t)b * NN + p];
  keep_out[(size_t)b * NN + orig] =
      ((keepw[b * 128 + (p >> 6)] >> (p & 63)) & 1) ? 1.0f : 0.0f;
}

// Slow-but-correct fallback if d_ws can't hold the mask.
__global__ __launch_bounds__(1024) void nms_fallback(
    const float4* __restrict__ sbox, const u64* __restrict__ vbits,
    const int* __restrict__ order, float* __restrict__ keep_out) {
  int b = blockIdx.x, tid = threadIdx.x;
  __shared__ u64 dead[128];
  __shared__ int s_next;
  __shared__ float4 s_box;
  for (int w = tid; w < 128; w += 1024) dead[w] = ~vbits[b * 128 + w];
  for (int p = tid; p < NN; p += 1024)
    keep_out[(size_t)b * NN + order[(size_t)b * NN + p]] = 0.0f;
  __syncthreads();
  int i = 0;
  while (true) {
    if (tid == 0) {
      int nxt = NN;
      int w = i >> 6;
      u64 live = ~dead[w] & (~0ull << (i & 63));
      while (true) {
        if (live) { nxt = w * 64 + __builtin_ctzll(live); break; }
        if (++w >= 128) break;
        live = ~dead[w];
      }
      s_next = nxt;
      if (nxt < NN) {
        s_box = sbox[(size_t)b * NN + nxt];
        keep_out[(size_t)b * NN + order[(size_t)b * NN + nxt]] = 1.0f;
      }
    }
    __syncthreads();
    i = s_next;
    if (i >= NN) break;
    float4 kb = s_box;
    for (int j = i + 1 + tid; j < NN; j += 1024) {
      if (iou_pair(kb, sbox[(size_t)b * NN + j]) > 0.5f)
        atomicOr(&dead[j >> 6], 1ull << (j & 63));
    }
    __syncthreads();
    i = i + 1;
  }
}

extern "C" void kernel_launch(void* const* d_in, const int* in_sizes, int n_in,
                              void* d_out, int out_size, void* d_ws, size_t ws_size,
                              hipStream_t stream) {
  const float* logits = (const float*)d_in[0];
  const float4* deltas = (const float4*)d_in[1];
  const float4* anchors = (const float4*)d_in[2];
  float* out = (float*)d_out;
  float4* boxes_out = (float4*)(out + OFF_BOXES);
  float* scores_out = out + OFF_SCORES;
  float* labels_out = out + OFF_LABELS;
  float* keep_out = out + OFF_KEEP;
  float* all_out = out + OFF_ALL;

  char* ws = (char*)d_ws;
  u64* keys = (u64*)(ws + WS_KEYS);
  unsigned char* vbyte = (unsigned char*)(ws + WS_VBYTE);
  int* order = (int*)(ws + WS_ORDER);
  float4* sbox = (float4*)(ws + WS_SBOX);
  u64* vbits = (u64*)(ws + WS_VBITS);
  u64* mask = (u64*)(ws + WS_MASK);
  u64* dnm = (u64*)(ws + WS_DNM);
  int* part = (int*)(ws + WS_PART);
  u64* rdarr = (u64*)(ws + WS_RD);
  unsigned short* csr = (unsigned short*)(ws + WS_CSR);
  unsigned int* cnt = (unsigned int*)(ws + WS_CNT);
  unsigned int* ovf = cnt + NB;
  u64* keepw = (u64*)(ws + WS_KEYS);  // reuses keys region (dead post-rank)

  decode_kernel<<<dim3(NB * NN / 4), dim3(256), 0, stream>>>(
      logits, deltas, anchors, boxes_out, scores_out, labels_out, all_out,
      keys, vbyte, vbits);
  if (ws_size >= WS_TOTAL_SPARSE) {
    rank_part_kernel<<<dim3(NN / 256, NSEG, NB), dim3(1024), 0, stream>>>(
        keys, part, dnm, cnt, ovf);
    rank_final_kernel<<<dim3(NN / 256, NB), dim3(256), 0, stream>>>(
        part, (const float4*)boxes_out, vbyte, order, sbox, vbits);
    build_kernel<<<dim3(128, 65, NB), dim3(64), 0, stream>>>(sbox, mask, dnm);
    fill_csr<<<dim3(NB * NN / 16), dim3(1024), 0, stream>>>(mask, rdarr, csr,
                                                            cnt, ovf);
    reduce_sparse<<<dim3(NB), dim3(64), 0, stream>>>(vbits, dnm, rdarr, csr,
                                                     ovf, keepw);
    reduce_dense<<<dim3(NB), dim3(512), 0, stream>>>(mask, vbits, dnm, ovf,
                                                     keepw);
    scatter_keep<<<dim3(NN / 256, NB), dim3(256), 0, stream>>>(keepw, order,
                                                               keep_out);
  } else if (ws_size >= WS_TOTAL) {
    rank_part_kernel<<<dim3(NN / 256, NSEG, NB), dim3(1024), 0, stream>>>(
        keys, part, dnm, nullptr, nullptr);
    rank_final_kernel<<<dim3(NN / 256, NB), dim3(256), 0, stream>>>(
        part, (const float4*)boxes_out, vbyte, order, sbox, vbits);
    build_kernel<<<dim3(128, 65, NB), dim3(64), 0, stream>>>(sbox, mask, dnm);
    reduce_dense<<<dim3(NB), dim3(512), 0, stream>>>(mask, vbits, dnm, nullptr,
                                                     keepw);
    scatter_keep<<<dim3(NN / 256, NB), dim3(256), 0, stream>>>(keepw, order,
                                                               keep_out);
  } else if (ws_size >= WS_TOTAL_OLD) {
    rank_kernel<<<dim3(NN / 256, NB), dim3(1024), 0, stream>>>(
        keys, (const float4*)boxes_out, vbyte, order, sbox, vbits, dnm);
    build_kernel<<<dim3(128, 65, NB), dim3(64), 0, stream>>>(sbox, mask, dnm);
    reduce_dense<<<dim3(NB), dim3(512), 0, stream>>>(mask, vbits, dnm, nullptr,
                                                     keepw);
    scatter_keep<<<dim3(NN / 256, NB), dim3(256), 0, stream>>>(keepw, order,
                                                               keep_out);
  } else {
    rank_kernel<<<dim3(NN / 256, NB), dim3(1024), 0, stream>>>(
        keys, (const float4*)boxes_out, vbyte, order, sbox, vbits, dnm);
    nms_fallback<<<dim3(NB), dim3(1024), 0, stream>>>(sbox, vbits, order,
                                                      keep_out);
  }
}

// Round 9
// 274.765 us; speedup vs baseline: 1.3910x; 1.3910x over previous
//
#include <hip/hip_runtime.h>

// Problem constants (fixed by reference): B=2, N=8192, C=80
constexpr int NB = 2;
constexpr int NN = 8192;
constexpr int NC = 80;
constexpr int ROWS = NN + 1;  // mask rows per batch; row NN is an all-zero row

// d_out layout (floats), in reference return order:
// boxes[B,N,4], max_scores[B,N], labels[B,N], keep[B,N], all_scores[B,N,C]
constexpr size_t OFF_BOXES  = 0;
constexpr size_t OFF_SCORES = (size_t)NB * NN * 4;
constexpr size_t OFF_LABELS = OFF_SCORES + (size_t)NB * NN;
constexpr size_t OFF_KEEP   = OFF_LABELS + (size_t)NB * NN;
constexpr size_t OFF_ALL    = OFF_KEEP + (size_t)NB * NN;

// d_ws layout
constexpr size_t WS_KEYS  = 0;                                   // B*N u64
constexpr size_t WS_VBYTE = WS_KEYS + (size_t)NB * NN * 8;       // B*N u8
constexpr size_t WS_ORDER = WS_VBYTE + (size_t)NB * NN;          // B*N i32
constexpr size_t WS_SBOX  = WS_ORDER + (size_t)NB * NN * 4;      // B*N float4
constexpr size_t WS_VBITS = WS_SBOX + (size_t)NB * NN * 16;      // B*128 u64
constexpr size_t WS_MASK  = WS_VBITS + (size_t)NB * 128 * 8;     // B*ROWS*128 u64
constexpr size_t WS_DNM   = WS_MASK + (size_t)NB * ROWS * 128 * 8; // B*128*4*64 u64
constexpr size_t WS_PART  = WS_DNM + (size_t)NB * 128 * 4 * 64 * 8; // B*8*N i32
constexpr size_t WS_TOTAL = WS_PART + (size_t)NB * 8 * NN * 4;
constexpr size_t WS_TOTAL_OLD = WS_PART;
// Sparse-NMS extension: per-row entry lists written directly by build.
constexpr int ROW_CAP = 64;  // entries per row (u16); deg>cap -> dense path
constexpr size_t WS_RDEG = WS_TOTAL;                              // B*N u32
constexpr size_t WS_RENT = WS_RDEG + (size_t)NB * NN * 4;         // B*N*64 u16
constexpr size_t WS_OVF  = WS_RENT + (size_t)NB * NN * ROW_CAP * 2;
constexpr size_t WS_TOTAL_SPARSE = WS_OVF + 64;
constexpr int DNM_WORDS = NB * 128 * 4 * 64;  // 65536
constexpr int NSEG = 8;                       // rank column segments

typedef unsigned long long u64;
typedef __attribute__((ext_vector_type(2))) unsigned long long u64x2;

// lgkmcnt(0)-only barrier: keeps global loads in flight across it.
__device__ inline void lbar() {
  __builtin_amdgcn_s_waitcnt(0xc07f);
  __builtin_amdgcn_s_barrier();
}

__device__ inline u64 readlane64(u64 v, int src) {
  unsigned int lo = (unsigned int)__builtin_amdgcn_readlane((int)(unsigned int)v, src);
  unsigned int hi = (unsigned int)__builtin_amdgcn_readlane((int)(unsigned int)(v >> 32), src);
  return ((u64)hi << 32) | lo;
}

__device__ inline u64 readfirstlane64(u64 v) {
  unsigned int lo = (unsigned int)__builtin_amdgcn_readfirstlane((int)(unsigned int)v);
  unsigned int hi = (unsigned int)__builtin_amdgcn_readfirstlane((int)(unsigned int)(v >> 32));
  return ((u64)hi << 32) | lo;
}

// IoU exactly mirroring the numpy op order; contraction off so f32 rounding
// matches numpy bit-for-bit. Bit-exactly SYMMETRIC in (p,q).
__device__ inline float iou_pair(const float4 p, const float4 q) {
#pragma clang fp contract(off)
  float areaA = (p.z - p.x) * (p.w - p.y);
  float areaB = (q.z - q.x) * (q.w - q.y);
  float ix1 = fmaxf(p.x, q.x);
  float iy1 = fmaxf(p.y, q.y);
  float ix2 = fminf(p.z, q.z);
  float iy2 = fminf(p.w, q.w);
  float inter = fmaxf(ix2 - ix1, 0.0f) * fmaxf(iy2 - iy1, 0.0f);
  float uni = areaA + areaB - inter;
  return inter / fmaxf(uni, 1e-9f);
}

__device__ inline float clip01(float v) { return fminf(fmaxf(v, 0.0f), 1.0f); }

// One wave per (b,n): sigmoid all 80 classes, max/argmax (first-index ties),
// box decode, validity, sort key. Also zero-inits vbits.
__global__ __launch_bounds__(256) void decode_kernel(
    const float* __restrict__ logits, const float4* __restrict__ deltas,
    const float4* __restrict__ anchors, float4* __restrict__ boxes_out,
    float* __restrict__ scores_out, float* __restrict__ labels_out,
    float* __restrict__ all_out, u64* __restrict__ keys,
    unsigned char* __restrict__ vbyte, u64* __restrict__ vbits) {
#pragma clang fp contract(off)
  if (blockIdx.x == 0 && threadIdx.x < NB * 128) vbits[threadIdx.x] = 0ull;
  int wid = (blockIdx.x * 256 + threadIdx.x) >> 6;  // 0 .. B*N-1
  int lane = threadIdx.x & 63;
  int n = wid & (NN - 1);
  size_t base = (size_t)wid * NC;

  float x0 = logits[base + lane];
  float sig0 = 1.0f / (1.0f + expf(-x0));
  all_out[base + lane] = sig0;
  float bs = sig0;
  int bidx = lane;
  if (lane < NC - 64) {
    float x1 = logits[base + 64 + lane];
    float sig1 = 1.0f / (1.0f + expf(-x1));
    all_out[base + 64 + lane] = sig1;
    if (sig1 > bs) { bs = sig1; bidx = lane + 64; }  // tie -> smaller idx wins
  }
  for (int off = 32; off; off >>= 1) {
    float os = __shfl_xor(bs, off, 64);
    int oi = __shfl_xor(bidx, off, 64);
    if (os > bs || (os == bs && oi < bidx)) { bs = os; bidx = oi; }
  }
  if (lane == 0) {
    float4 d = deltas[wid];
    float4 a = anchors[n];
    float aw = a.z - a.x, ah = a.w - a.y;
    float acx = a.x + 0.5f * aw, acy = a.y + 0.5f * ah;
    float dw = fminf(d.z, 4.0f), dh = fminf(d.w, 4.0f);
    float pcx = d.x * aw + acx;
    float pcy = d.y * ah + acy;
    float pw = expf(dw) * aw;
    float ph = expf(dh) * ah;
    float4 bx;
    bx.x = clip01(pcx - 0.5f * pw);
    bx.y = clip01(pcy - 0.5f * ph);
    bx.z = clip01(pcx + 0.5f * pw);
    bx.w = clip01(pcy + 0.5f * ph);
    boxes_out[wid] = bx;
    scores_out[wid] = bs;
    labels_out[wid] = (float)bidx;
    float bw = bx.z - bx.x, bh = bx.w - bx.y;
    bool valid = (bs > 0.5f) && (bw > 0.01f) && (bh > 0.01f) &&
                 (bw < 0.99f) && (bh < 0.99f);
    vbyte[wid] = valid ? 1 : 0;
    keys[wid] = ((u64)__float_as_uint(bs) << 32) | (unsigned int)(NN - 1 - n);
  }
}

// Rank pass 1: partial counts over a column SEGMENT. Also zero-inits dnm
// and (if provided) rowdeg/ovf for the sparse path.
__global__ __launch_bounds__(1024) void rank_part_kernel(
    const u64* __restrict__ keys, int* __restrict__ part,
    u64* __restrict__ dnm, unsigned int* rowdeg, unsigned int* ovf) {
  int b = blockIdx.z, seg = blockIdx.y, rb = blockIdx.x;
  int gid = ((blockIdx.z * NSEG + blockIdx.y) * gridDim.x + blockIdx.x) * 1024 +
            threadIdx.x;
  if (gid < DNM_WORDS) dnm[gid] = 0ull;
  if (rowdeg) {
    if (gid < NB * NN) rowdeg[gid] = 0u;
    if (gid < NB) ovf[gid] = 0u;
  }
  int r = threadIdx.x & 255;   // row slot
  int q = threadIdx.x >> 8;    // column quarter 0..3 (wave-uniform)
  int i = rb * 256 + r;
  const u64* kb = keys + (size_t)b * NN;
  u64 myk = kb[i];
  int cnt2 = 0;
  int j0 = seg * (NN / NSEG) + q * (NN / NSEG / 4);
  int j1 = j0 + NN / NSEG / 4;  // 256 iterations
#pragma unroll 8
  for (int j = j0; j < j1; ++j) {
    u64 kj = kb[j];  // wave-uniform address -> scalar load
    cnt2 += (kj > myk) ? 1 : 0;
  }
  __shared__ unsigned short partl[4][256];
  partl[q][r] = (unsigned short)cnt2;
  __syncthreads();
  if (threadIdx.x < 256) {
    int s = partl[0][r] + partl[1][r] + partl[2][r] + partl[3][r];
    part[((size_t)b * NSEG + seg) * NN + i] = s;
  }
}

// Rank pass 2: rank = sum of segment partials; scatter order/sbox/vbits.
__global__ __launch_bounds__(256) void rank_final_kernel(
    const int* __restrict__ part, const float4* __restrict__ boxes,
    const unsigned char* __restrict__ vbyte, int* __restrict__ order,
    float4* __restrict__ sbox, u64* __restrict__ vbits) {
  int b = blockIdx.y;
  int i = blockIdx.x * 256 + threadIdx.x;
  const int* pb = part + (size_t)b * NSEG * NN + i;
  int rank = 0;
#pragma unroll
  for (int s = 0; s < NSEG; ++s) rank += pb[(size_t)s * NN];
  order[(size_t)b * NN + rank] = i;
  sbox[(size_t)b * NN + rank] = boxes[(size_t)b * NN + i];
  if (vbyte[(size_t)b * NN + i])
    atomicOr(&vbits[b * 128 + (rank >> 6)], 1ull << (rank & 63));
}

// Monolithic rank (fallback path only, when ws can't hold part[]).
__global__ __launch_bounds__(1024) void rank_kernel(
    const u64* __restrict__ keys, const float4* __restrict__ boxes,
    const unsigned char* __restrict__ vbyte, int* __restrict__ order,
    float4* __restrict__ sbox, u64* __restrict__ vbits,
    u64* __restrict__ dnm) {
  int b = blockIdx.y;
  int gid = (blockIdx.y * gridDim.x + blockIdx.x) * 1024 + threadIdx.x;
  for (int z = gid; z < DNM_WORDS; z += 65536) dnm[z] = 0ull;
  int r = threadIdx.x & 255;
  int q = threadIdx.x >> 8;
  int i = blockIdx.x * 256 + r;
  const u64* kb = keys + (size_t)b * NN;
  u64 myk = kb[i];
  int cnt = 0;
  int j0 = q * (NN / 4), j1 = j0 + NN / 4;
#pragma unroll 8
  for (int j = j0; j < j1; ++j) {
    u64 kj = kb[j];
    cnt += (kj > myk) ? 1 : 0;
  }
  __shared__ unsigned short part[4][256];
  part[q][r] = (unsigned short)cnt;
  __syncthreads();
  if (threadIdx.x < 256) {
    int rank = part[0][r] + part[1][r] + part[2][r] + part[3][r];
    order[(size_t)b * NN + rank] = i;
    sbox[(size_t)b * NN + rank] = boxes[(size_t)b * NN + i];
    if (vbyte[(size_t)b * NN + i])
      atomicOr(&vbits[b * 128 + (rank >> 6)], 1ull << (rank & 63));
  }
}

// 64x64 tile of the (sorted-order) suppression matrix. Triangular grid.
// Diagonal tiles: upper half (self cleared) to mask[], lower half to dnm
// slot 0 (fixpoint masks). Off-diag bx>by: full word to mask[]; dq<4 also
// to dnm. NEW (sparse path): each tile also appends its upper-triangle
// column indices (j>i) to the row's fixed 64-entry list via one global
// atomicAdd reservation; overflow (deg>64) sets ovf[b] -> dense fallback.
// Entry order within a row is arbitrary (deposits are ORs).
__global__ __launch_bounds__(64) void build_kernel(
    const float4* __restrict__ sbox, u64* __restrict__ mask,
    u64* __restrict__ dnm, unsigned int* rowdeg,
    unsigned short* rowent, unsigned int* ovf) {
  int byq = blockIdx.y, bxq = blockIdx.x, b = blockIdx.z;
  int by, bx;
  if (bxq >= byq) {
    by = byq; bx = bxq;
  } else if (byq == 64) {
    return;
  } else {
    by = 128 - byq; bx = 127 - bxq;
  }
  int lane = threadIdx.x;
  __shared__ float4 cb[64];
  cb[lane] = sbox[(size_t)b * NN + bx * 64 + lane];
  __syncthreads();
  int i = by * 64 + lane;
  float4 rb = sbox[(size_t)b * NN + i];
  u64 word = 0;
  for (int jj = 0; jj < 64; ++jj)
    if (iou_pair(rb, cb[jj]) > 0.5f) word |= 1ull << jj;
  u64 ent;
  if (bx == by) {
    word &= ~(1ull << lane);  // clear self-IoU bit
    u64 lmask = (1ull << lane) - 1ull;
    mask[((size_t)b * ROWS + i) * 128 + bx] = word & ~lmask;
    dnm[(((size_t)b * 128 + by) * 4 + 0) * 64 + lane] = word & lmask;
    ent = word & ~lmask;  // j > i only
  } else {
    mask[((size_t)b * ROWS + i) * 128 + bx] = word;
    int dq = bx - by;
    if (dq < 4) dnm[(((size_t)b * 128 + by) * 4 + dq) * 64 + lane] = word;
    ent = word;  // whole tile is j > i
  }
  if (rowdeg && ent) {
    int wcnt = __popcll(ent);
    unsigned base = atomicAdd(&rowdeg[(size_t)b * NN + i], (unsigned)wcnt);
    if (base + (unsigned)wcnt <= (unsigned)ROW_CAP) {
      unsigned short* dst = rowent + ((size_t)b * NN + i) * ROW_CAP + base;
      int k = 0;
      u64 t = ent;
      while (t) {
        int bit = __builtin_ctzll(t);
        dst[k++] = (unsigned short)(bx * 64 + bit);
        t &= t - 1;
      }
    } else {
      atomicOr(&ovf[b], 1u);
    }
  }
}

// Sparse greedy reduce: ONE 64-lane wave per batch, ZERO barriers.
// Per chunk c: ballot fixpoint on the lower-triangle diag mask (dnm slot 0);
// each KEPT lane LDS-atomicOrs its row's entry list (all j>r with IoU>0.5)
// into s_remv. Single wave => DS ops are in-order, so deposits at body c are
// visible to the s_remv[c+1] read at body c+1 with no synchronization.
// Plain-C++ 4-slot rotating prefetch (v10-proven pattern; NO inline asm --
// the asm-tie version spilled to scratch, VGPR_Count 36, 31 ms). Loads for
// chunk c+2 (diag, deg, first 32 entries -- all static addresses) issue at
// body c. deg in (32,64] takes a rare global slow path; deg>64 set ovf[b]
// in build and the dense kernel handles that batch.
__global__ __launch_bounds__(64) void reduce_sparse(
    const u64* __restrict__ vbits, const u64* __restrict__ dnm,
    const unsigned int* __restrict__ rowdeg,
    const unsigned short* __restrict__ rowent,
    const unsigned int* __restrict__ ovf, u64* __restrict__ keepw) {
  int b = blockIdx.x, lane = threadIdx.x;
  if (ovf[b]) return;  // dense fallback handles this batch
  __shared__ u64 s_remv[128];
  __shared__ u64 s_keep[128];
  s_remv[2 * lane] = 0ull;
  s_remv[2 * lane + 1] = 0ull;
  u64 va = vbits[b * 128 + 2 * lane];
  u64 vb2 = vbits[b * 128 + 2 * lane + 1];
  const u64* dnb = dnm + (size_t)b * 128 * 4 * 64;
  const unsigned int* dgb = rowdeg + (size_t)b * NN;
  const unsigned short* reb = rowent + (size_t)b * NN * ROW_CAP;

  // Prologue: chunks 0 and 1 into slots A,B.
  u64 dA = dnb[lane];
  unsigned gA = dgb[lane];
  const u64x2* pA = (const u64x2*)(reb + (size_t)lane * ROW_CAP);
  u64x2 eA0 = pA[0], eA1 = pA[1], eA2 = pA[2], eA3 = pA[3];
  u64 dB = dnb[4 * 64 + lane];
  unsigned gB = dgb[64 + lane];
  const u64x2* pB = (const u64x2*)(reb + (size_t)(64 + lane) * ROW_CAP);
  u64x2 eB0 = pB[0], eB1 = pB[1], eB2 = pB[2], eB3 = pB[3];
  u64 dC = 0, dD = 0;
  unsigned gC = 0, gD = 0;
  u64x2 eC0{}, eC1{}, eC2{}, eC3{}, eD0{}, eD1{}, eD2{}, eD3{};

  auto body = [&](int c, u64 dcur, unsigned gcur, u64x2 e0, u64x2 e1,
                  u64x2 e2, u64x2 e3, u64& dnw, unsigned& gnw, u64x2& n0,
                  u64x2& n1, u64x2& n2, u64x2& n3) {
    // Prefetch chunk c+2 into the rotating slot (clamped; never consumed
    // past the loop end).
    int cp = (c + 2 < 128) ? c + 2 : 127;
    dnw = dnb[(size_t)cp * 4 * 64 + lane];
    gnw = dgb[cp * 64 + lane];
    const u64x2* np = (const u64x2*)(reb + (size_t)(cp * 64 + lane) * ROW_CAP);
    n0 = np[0]; n1 = np[1]; n2 = np[2]; n3 = np[3];
    u64 rm = s_remv[c];
    u64 vbw = readlane64((c & 1) ? vb2 : va, c >> 1);
    u64 cand = readfirstlane64(vbw & ~rm);
    // Ballot fixpoint: dcur = lane's lower-triangle column mask.
    u64 kept = cand;
    while (true) {
      u64 sup = __ballot((dcur & kept) != 0ull);
      u64 nk = cand & ~sup;
      if (nk == kept) break;
      kept = nk;
    }
    bool isk = (kept >> lane) & 1;
    int deg = (int)gcur;
    if (isk && deg > 0) {
      int lim = deg < 32 ? deg : 32;
#pragma unroll
      for (int k = 0; k < 32; ++k) {
        if (k < lim) {
          u64 src = (k < 16)
                        ? ((k < 8) ? ((k < 4) ? e0[0] : e0[1])
                                   : ((k < 12) ? e1[0] : e1[1]))
                        : ((k < 24) ? ((k < 20) ? e2[0] : e2[1])
                                    : ((k < 28) ? e3[0] : e3[1]));
          int j = (int)((src >> ((k & 3) * 16)) & 0xFFFFull);
          atomicOr(&s_remv[j >> 6], 1ull << (j & 63));
        }
      }
      for (int k = 32; k < deg; ++k) {  // rare (deg in (32,64])
        int j = reb[(size_t)(c * 64 + lane) * ROW_CAP + k];
        atomicOr(&s_remv[j >> 6], 1ull << (j & 63));
      }
    }
    if (lane == 0) s_keep[c] = kept;
  };

  for (int c = 0; c < 128; c += 4) {
    body(c + 0, dA, gA, eA0, eA1, eA2, eA3, dC, gC, eC0, eC1, eC2, eC3);
    body(c + 1, dB, gB, eB0, eB1, eB2, eB3, dD, gD, eD0, eD1, eD2, eD3);
    body(c + 2, dC, gC, eC0, eC1, eC2, eC3, dA, gA, eA0, eA1, eA2, eA3);
    body(c + 3, dD, gD, eD0, eD1, eD2, eD3, dB, gB, eB0, eB1, eB2, eB3);
  }

  keepw[b * 128 + 2 * lane] = s_keep[2 * lane];
  keepw[b * 128 + 2 * lane + 1] = s_keep[2 * lane + 1];
}

struct TSet {
  u64x2 t0, t1, t2, t3, t4, t5, t6, t7, t8, t9;
};

// Dense greedy reduce (v13 machinery) — overflow/small-ws fallback.
// If ovf != nullptr it runs ONLY when ovf[b] is set.
__global__ __launch_bounds__(512) void reduce_dense(
    u64* __restrict__ mask, const u64* __restrict__ vbits,
    const u64* __restrict__ dnm, const unsigned int* __restrict__ ovf,
    u64* __restrict__ keepw) {
  int b = blockIdx.x, tid = threadIdx.x;
  if (ovf && ovf[b] == 0) return;
  int lane = tid & 63, wave = tid >> 6;
  __shared__ u64 s_remv[128];
  __shared__ u64 s_keep[128];
  __shared__ int s_rowlist[2][80];
  u64* mbz = mask + (size_t)b * ROWS * 128;
  const u64* mb = mbz;
  const u64* dn = dnm + (size_t)b * 128 * 4 * 64;

  for (int w = tid; w < 128; w += 512) {
    s_remv[w] = 0ull;
    mbz[(size_t)NN * 128 + w] = 0ull;  // zero row (dead-load target)
  }
  if (tid < 160) s_rowlist[tid / 80][tid % 80] = NN;

  u64 va = 0, vb2 = 0;
  u64 dA = 0, nA = 0, mA = 0, oA = 0, dB = 0, nB = 0, mB = 0, oB = 0;
  u64 dC = 0, nC = 0, mC = 0, oC = 0, dD = 0, nD = 0, mD = 0, oD = 0;
  if (wave == 0) {
    va = vbits[b * 128 + 2 * lane];
    vb2 = vbits[b * 128 + 2 * lane + 1];
    const u64* r0 = dn + lane;
    dA = r0[0]; nA = r0[64]; mA = r0[128]; oA = r0[192];
    const u64* r1 = dn + 4 * 64 + lane;
    dB = r1[0]; nB = r1[64]; mB = r1[128]; oB = r1[192];
  }
  TSet U{}, V{};
  int w0i = 2 * lane;
  __syncthreads();

  auto serial_body = [&](int c, u64 dcur, u64 ncur, u64 mcur, u64 ocur,
                         u64& dnew, u64& nnew, u64& mnew, u64& onew) {
    int cp = (c + 2 < 128) ? (c + 2) : 127;
    const u64* rp = dn + (size_t)cp * 4 * 64 + lane;
    dnew = rp[0]; nnew = rp[64]; mnew = rp[128]; onew = rp[192];
    int par = c & 1;
    u64 rm = s_remv[c];
    u64 vbw = readlane64(par ? vb2 : va, c >> 1);
    u64 cand = readfirstlane64(vbw & ~rm);
    u64 kept = cand;
    while (true) {
      u64 sup = __ballot((dcur & kept) != 0ull);
      u64 nk = cand & ~sup;
      if (nk == kept) break;
      kept = nk;
    }
    bool isk = (kept >> lane) & 1;
    if (c + 1 < 128 && isk && ncur) atomicOr(&s_remv[c + 1], ncur);
    if (c + 2 < 128 && isk && mcur) atomicOr(&s_remv[c + 2], mcur);
    if (c + 3 < 128 && isk && ocur) atomicOr(&s_remv[c + 3], ocur);
    s_rowlist[par][lane] = NN;
    if (isk) {
      int pos = __popcll(kept & ((1ull << lane) - 1ull));
      s_rowlist[par][pos] = c * 64 + lane;
    }
    if (lane == 0) s_keep[c] = kept;
  };

  auto bg_body = [&](int c, TSet& T) {
    u64 ax = T.t0[0] | T.t1[0] | T.t2[0] | T.t3[0] | T.t4[0] | T.t5[0] |
             T.t6[0] | T.t7[0] | T.t8[0] | T.t9[0];
    u64 ay = T.t0[1] | T.t1[1] | T.t2[1] | T.t3[1] | T.t4[1] | T.t5[1] |
             T.t6[1] | T.t7[1] | T.t8[1] | T.t9[1];
    int sc = (c + 1) & ~1;
    int wx = sc + w0i, wy = wx + 1;
    if (wx > c && wx < 128 && ax) atomicOr(&s_remv[wx], ax);
    if (wy > c && wy < 128 && ay) atomicOr(&s_remv[wy], ay);
    const int* rl = s_rowlist[(c - 1) & 1];
    int base = wave - 1;
    int si = (c + 3) & ~1;
    int w = si + w0i;
    bool wok = w < 128;
    const u64* mw = mb + w;
    const u64* zp = mbz + (size_t)NN * 128;
    int r0 = rl[base], r1 = rl[base + 7], r2 = rl[base + 14],
        r3 = rl[base + 21], r4 = rl[base + 28], r5 = rl[base + 35],
        r6 = rl[base + 42], r7 = rl[base + 49], r8 = rl[base + 56],
        r9 = rl[base + 63];
    T.t0 = *(const u64x2*)((wok && r0 != NN) ? mw + (size_t)r0 * 128 : zp);
    T.t1 = *(const u64x2*)((wok && r1 != NN) ? mw + (size_t)r1 * 128 : zp);
    T.t2 = *(const u64x2*)((wok && r2 != NN) ? mw + (size_t)r2 * 128 : zp);
    T.t3 = *(const u64x2*)((wok && r3 != NN) ? mw + (size_t)r3 * 128 : zp);
    T.t4 = *(const u64x2*)((wok && r4 != NN) ? mw + (size_t)r4 * 128 : zp);
    T.t5 = *(const u64x2*)((wok && r5 != NN) ? mw + (size_t)r5 * 128 : zp);
    T.t6 = *(const u64x2*)((wok && r6 != NN) ? mw + (size_t)r6 * 128 : zp);
    T.t7 = *(const u64x2*)((wok && r7 != NN) ? mw + (size_t)r7 * 128 : zp);
    T.t8 = *(const u64x2*)((wok && r8 != NN) ? mw + (size_t)r8 * 128 : zp);
    T.t9 = *(const u64x2*)((wok && r9 != NN) ? mw + (size_t)r9 * 128 : zp);
  };

  for (int c = 0; c < 128; c += 4) {
    if (wave == 0) serial_body(c, dA, nA, mA, oA, dC, nC, mC, oC);
    else bg_body(c, U);
    lbar();
    if (wave == 0) serial_body(c + 1, dB, nB, mB, oB, dD, nD, mD, oD);
    else bg_body(c + 1, V);
    lbar();
    if (wave == 0) serial_body(c + 2, dC, nC, mC, oC, dA, nA, mA, oA);
    else bg_body(c + 2, U);
    lbar();
    if (wave == 0) serial_body(c + 3, dD, nD, mD, oD, dB, nB, mB, oB);
    else bg_body(c + 3, V);
    lbar();
  }

  __syncthreads();
  for (int w = tid; w < 128; w += 512) keepw[b * 128 + w] = s_keep[w];
}

// Scatter keep bits back to original anchor order (parallel epilogue).
__global__ __launch_bounds__(256) void scatter_keep(
    const u64* __restrict__ keepw, const int* __restrict__ order,
    float* __restrict__ keep_out) {
  int b = blockIdx.y;
  int p = blockIdx.x * 256 + threadIdx.x;
  int orig = order[(size_t)b * NN + p];
  keep_out[(size_t)b * NN + orig] =
      ((keepw[b * 128 + (p >> 6)] >> (p & 63)) & 1) ? 1.0f : 0.0f;
}

// Slow-but-correct fallback if d_ws can't hold the mask.
__global__ __launch_bounds__(1024) void nms_fallback(
    const float4* __restrict__ sbox, const u64* __restrict__ vbits,
    const int* __restrict__ order, float* __restrict__ keep_out) {
  int b = blockIdx.x, tid = threadIdx.x;
  __shared__ u64 dead[128];
  __shared__ int s_next;
  __shared__ float4 s_box;
  for (int w = tid; w < 128; w += 1024) dead[w] = ~vbits[b * 128 + w];
  for (int p = tid; p < NN; p += 1024)
    keep_out[(size_t)b * NN + order[(size_t)b * NN + p]] = 0.0f;
  __syncthreads();
  int i = 0;
  while (true) {
    if (tid == 0) {
      int nxt = NN;
      int w = i >> 6;
      u64 live = ~dead[w] & (~0ull << (i & 63));
      while (true) {
        if (live) { nxt = w * 64 + __builtin_ctzll(live); break; }
        if (++w >= 128) break;
        live = ~dead[w];
      }
      s_next = nxt;
      if (nxt < NN) {
        s_box = sbox[(size_t)b * NN + nxt];
        keep_out[(size_t)b * NN + order[(size_t)b * NN + nxt]] = 1.0f;
      }
    }
    __syncthreads();
    i = s_next;
    if (i >= NN) break;
    float4 kb = s_box;
    for (int j = i + 1 + tid; j < NN; j += 1024) {
      if (iou_pair(kb, sbox[(size_t)b * NN + j]) > 0.5f)
        atomicOr(&dead[j >> 6], 1ull << (j & 63));
    }
    __syncthreads();
    i = i + 1;
  }
}

extern "C" void kernel_launch(void* const* d_in, const int* in_sizes, int n_in,
                              void* d_out, int out_size, void* d_ws, size_t ws_size,
                              hipStream_t stream) {
  const float* logits = (const float*)d_in[0];
  const float4* deltas = (const float4*)d_in[1];
  const float4* anchors = (const float4*)d_in[2];
  float* out = (float*)d_out;
  float4* boxes_out = (float4*)(out + OFF_BOXES);
  float* scores_out = out + OFF_SCORES;
  float* labels_out = out + OFF_LABELS;
  float* keep_out = out + OFF_KEEP;
  float* all_out = out + OFF_ALL;

  char* ws = (char*)d_ws;
  u64* keys = (u64*)(ws + WS_KEYS);
  unsigned char* vbyte = (unsigned char*)(ws + WS_VBYTE);
  int* order = (int*)(ws + WS_ORDER);
  float4* sbox = (float4*)(ws + WS_SBOX);
  u64* vbits = (u64*)(ws + WS_VBITS);
  u64* mask = (u64*)(ws + WS_MASK);
  u64* dnm = (u64*)(ws + WS_DNM);
  int* part = (int*)(ws + WS_PART);
  unsigned int* rowdeg = (unsigned int*)(ws + WS_RDEG);
  unsigned short* rowent = (unsigned short*)(ws + WS_RENT);
  unsigned int* ovf = (unsigned int*)(ws + WS_OVF);
  u64* keepw = (u64*)(ws + WS_KEYS);  // reuses keys region (dead post-rank)

  decode_kernel<<<dim3(NB * NN / 4), dim3(256), 0, stream>>>(
      logits, deltas, anchors, boxes_out, scores_out, labels_out, all_out,
      keys, vbyte, vbits);
  if (ws_size >= WS_TOTAL_SPARSE) {
    rank_part_kernel<<<dim3(NN / 256, NSEG, NB), dim3(1024), 0, stream>>>(
        keys, part, dnm, rowdeg, ovf);
    rank_final_kernel<<<dim3(NN / 256, NB), dim3(256), 0, stream>>>(
        part, (const float4*)boxes_out, vbyte, order, sbox, vbits);
    build_kernel<<<dim3(128, 65, NB), dim3(64), 0, stream>>>(
        sbox, mask, dnm, rowdeg, rowent, ovf);
    reduce_sparse<<<dim3(NB), dim3(64), 0, stream>>>(vbits, dnm, rowdeg,
                                                     rowent, ovf, keepw);
    reduce_dense<<<dim3(NB), dim3(512), 0, stream>>>(mask, vbits, dnm, ovf,
                                                     keepw);
    scatter_keep<<<dim3(NN / 256, NB), dim3(256), 0, stream>>>(keepw, order,
                                                               keep_out);
  } else if (ws_size >= WS_TOTAL) {
    rank_part_kernel<<<dim3(NN / 256, NSEG, NB), dim3(1024), 0, stream>>>(
        keys, part, dnm, nullptr, nullptr);
    rank_final_kernel<<<dim3(NN / 256, NB), dim3(256), 0, stream>>>(
        part, (const float4*)boxes_out, vbyte, order, sbox, vbits);
    build_kernel<<<dim3(128, 65, NB), dim3(64), 0, stream>>>(
        sbox, mask, dnm, nullptr, nullptr, nullptr);
    reduce_dense<<<dim3(NB), dim3(512), 0, stream>>>(mask, vbits, dnm, nullptr,
                                                     keepw);
    scatter_keep<<<dim3(NN / 256, NB), dim3(256), 0, stream>>>(keepw, order,
                                                               keep_out);
  } else if (ws_size >= WS_TOTAL_OLD) {
    rank_kernel<<<dim3(NN / 256, NB), dim3(1024), 0, stream>>>(
        keys, (const float4*)boxes_out, vbyte, order, sbox, vbits, dnm);
    build_kernel<<<dim3(128, 65, NB), dim3(64), 0, stream>>>(
        sbox, mask, dnm, nullptr, nullptr, nullptr);
    reduce_dense<<<dim3(NB), dim3(512), 0, stream>>>(mask, vbits, dnm, nullptr,
                                                     keepw);
    scatter_keep<<<dim3(NN / 256, NB), dim3(256), 0, stream>>>(keepw, order,
                                                               keep_out);
  } else {
    rank_kernel<<<dim3(NN / 256, NB), dim3(1024), 0, stream>>>(
        keys, (const float4*)boxes_out, vbyte, order, sbox, vbits, dnm);
    nms_fallback<<<dim3(NB), dim3(1024), 0, stream>>>(sbox, vbits, order,
                                                      keep_out);
  }
}